// Round 2
// baseline (1254.510 us; speedup 1.0000x reference)
//
#include <hip/hip_runtime.h>
#include <math.h>

#define NN 50000
#define NE 800000

__device__ __forceinline__ float elu1(float x) { return x > 0.f ? x : expm1f(x); }
__device__ __forceinline__ float lrelu(float x) { return x >= 0.f ? x : 0.2f * x; }

__global__ __launch_bounds__(256) void zero_kernel(float* __restrict__ p, int n) {
  int i = blockIdx.x * blockDim.x + threadIdx.x;
  int stride = gridDim.x * blockDim.x;
  for (; i < n; i += stride) p[i] = 0.f;
}

// zero two disjoint regions in one launch
__global__ __launch_bounds__(256) void zero2_kernel(float* __restrict__ p0, int n0,
                                                    float* __restrict__ p1, int n1) {
  int i = blockIdx.x * blockDim.x + threadIdx.x;
  int stride = gridDim.x * blockDim.x;
  for (int j = i; j < n0; j += stride) p0[j] = 0.f;
  for (int j = i; j < n1; j += stride) p1[j] = 0.f;
}

// Fold node_f linear into layer-1 fs/fd linears:
//   Wns = Wn @ W1s, bns = bn @ W1s + b1s  (same for d)
__global__ __launch_bounds__(256) void combine_weights(
    const float* __restrict__ Wn, const float* __restrict__ bn,
    const float* __restrict__ W1s, const float* __restrict__ b1s,
    const float* __restrict__ W1d, const float* __restrict__ b1d,
    float* __restrict__ Wns, float* __restrict__ Wnd,
    float* __restrict__ bns, float* __restrict__ bnd) {
  int t = blockIdx.x * blockDim.x + threadIdx.x;
  if (t < 8192) {
    int i = t >> 6, o = t & 63;
    float acc = 0.f;
    for (int k = 0; k < 128; ++k) acc += Wn[i * 128 + k] * W1s[k * 64 + o];
    Wns[t] = acc;
  } else if (t < 16384) {
    int u = t - 8192;
    int i = u >> 6, o = u & 63;
    float acc = 0.f;
    for (int k = 0; k < 128; ++k) acc += Wn[i * 128 + k] * W1d[k * 64 + o];
    Wnd[u] = acc;
  } else if (t < 16448) {
    int o = t - 16384;
    float acc = b1s[o];
    for (int k = 0; k < 128; ++k) acc += bn[k] * W1s[k * 64 + o];
    bns[o] = acc;
  } else if (t < 16512) {
    int o = t - 16448;
    float acc = b1d[o];
    for (int k = 0; k < 128; ++k) acc += bn[k] * W1d[k * 64 + o];
    bnd[o] = acc;
  }
}

// deg[0:N)=wdeg_out, [N:2N)=wdeg_in, [2N:3N)=cnt_out, [3N:4N)=cnt_in
__global__ __launch_bounds__(256) void degrees_kernel(const float* __restrict__ ew,
                                                      const int* __restrict__ src,
                                                      const int* __restrict__ dst,
                                                      float* __restrict__ deg) {
  int e = blockIdx.x * blockDim.x + threadIdx.x;
  if (e >= NE) return;
  float w = ew[e];
  int s = src[e], d = dst[e];
  atomicAdd(&deg[s], w);
  atomicAdd(&deg[NN + d], w);
  atomicAdd(&deg[2 * NN + s], 1.f);
  atomicAdd(&deg[3 * NN + d], 1.f);
}

// Y[N,M] = (ELU_IN? elu(X) : X)[N,K] @ W[K,M] (+b) (* rsqrt(max(cnt,1)) if RS_OUT)
template <int K, int M, bool ELU_IN, bool RS_OUT>
__global__ __launch_bounds__(256) void node_gemm(const float* __restrict__ X,
                                                 const float* __restrict__ W,
                                                 const float* __restrict__ b,
                                                 const float* __restrict__ cnt,
                                                 float* __restrict__ Y) {
  constexpr int ROWS = 256 / M;
  __shared__ float xs[ROWS][K];
  int row0 = blockIdx.x * ROWS;
  int t = threadIdx.x;
  for (int idx = t; idx < ROWS * K; idx += 256) {
    int r = idx / K, k = idx - r * K;
    int row = row0 + r;
    float v = (row < NN) ? X[row * K + k] : 0.f;
    if (ELU_IN) v = elu1(v);
    xs[r][k] = v;
  }
  __syncthreads();
  int r = t / M, m = t - (t / M) * M;
  int row = row0 + r;
  if (row >= NN) return;
  float acc = b ? b[m] : 0.f;
#pragma unroll
  for (int k = 0; k < K; ++k) acc += xs[r][k] * W[k * M + m];
  if (RS_OUT) acc *= 1.f / sqrtf(fmaxf(cnt[row], 1.f));
  Y[row * M + m] = acc;
}

// ---- GATv2 layer 1 (2 heads x 32 dims), wave(64) per edge ----
__global__ __launch_bounds__(256) void gat1_logits(const int* __restrict__ src,
                                                   const int* __restrict__ dst,
                                                   const float* __restrict__ fs,
                                                   const float* __restrict__ fd,
                                                   const float* __restrict__ attn,
                                                   float* __restrict__ p, float* __restrict__ ssum) {
  int lane = threadIdx.x & 63;
  int e = blockIdx.x * 4 + (threadIdx.x >> 6);
  if (e >= NE) return;
  int s = src[e], d = dst[e];
  float v = lrelu(fs[s * 64 + lane] + fd[d * 64 + lane]) * attn[lane];
#pragma unroll
  for (int m = 16; m >= 1; m >>= 1) v += __shfl_xor(v, m, 64);
  if ((lane & 31) == 0) {
    float pv = expf(v);  // softmax shift-invariant; logits tiny -> no max pass
    int hh = lane >> 5;
    p[e * 2 + hh] = pv;
    atomicAdd(&ssum[d * 2 + hh], pv);
  }
}

__global__ __launch_bounds__(256) void gat1_agg(const int* __restrict__ src,
                                                const int* __restrict__ dst,
                                                const float* __restrict__ fs,
                                                const float* __restrict__ p,
                                                const float* __restrict__ ssum,
                                                float* __restrict__ g) {
  int lane = threadIdx.x & 63;
  int e = blockIdx.x * 4 + (threadIdx.x >> 6);
  if (e >= NE) return;
  int s = src[e], d = dst[e];
  int hh = lane >> 5;
  float alpha = p[e * 2 + hh] / ssum[d * 2 + hh];
  atomicAdd(&g[d * 64 + lane], fs[s * 64 + lane] * alpha);
}

// ---- GATv2 layer 2 (1 head x 64 dims) ----
__global__ __launch_bounds__(256) void gat2_logits(const int* __restrict__ src,
                                                   const int* __restrict__ dst,
                                                   const float* __restrict__ fs,
                                                   const float* __restrict__ fd,
                                                   const float* __restrict__ attn,
                                                   float* __restrict__ p, float* __restrict__ ssum) {
  int lane = threadIdx.x & 63;
  int e = blockIdx.x * 4 + (threadIdx.x >> 6);
  if (e >= NE) return;
  int s = src[e], d = dst[e];
  float v = lrelu(fs[s * 64 + lane] + fd[d * 64 + lane]) * attn[lane];
#pragma unroll
  for (int m = 32; m >= 1; m >>= 1) v += __shfl_xor(v, m, 64);
  if (lane == 0) {
    float pv = expf(v);
    p[e] = pv;
    atomicAdd(&ssum[d], pv);
  }
}

__global__ __launch_bounds__(256) void gat2_agg(const int* __restrict__ src,
                                                const int* __restrict__ dst,
                                                const float* __restrict__ fs,
                                                const float* __restrict__ p,
                                                const float* __restrict__ ssum,
                                                float* __restrict__ g) {
  int lane = threadIdx.x & 63;
  int e = blockIdx.x * 4 + (threadIdx.x >> 6);
  if (e >= NE) return;
  int s = src[e], d = dst[e];
  float alpha = p[e] / ssum[d];
  atomicAdd(&g[d * 64 + lane], fs[s * 64 + lane] * alpha);
}

// GraphConv norm='none' with edge weight: c1[dst] += xm[src]*norm_w
__global__ __launch_bounds__(256) void gconv1_kernel(const int* __restrict__ src,
                                                     const int* __restrict__ dst,
                                                     const float* __restrict__ ew,
                                                     const float* __restrict__ deg,
                                                     const float* __restrict__ xm,
                                                     float* __restrict__ c1) {
  int t = blockIdx.x * blockDim.x + threadIdx.x;
  int e = t >> 5, f = t & 31;
  if (e >= NE) return;
  int s = src[e], d = dst[e];
  float nw = ew[e] * (1.f / sqrtf(deg[s])) * (1.f / sqrtf(deg[NN + d]));
  atomicAdd(&c1[d * 32 + f], xm[s * 32 + f] * nw);
}

__global__ __launch_bounds__(256) void elu_bias32(const float* __restrict__ in,
                                                  const float* __restrict__ b,
                                                  float* __restrict__ out) {
  int i = blockIdx.x * blockDim.x + threadIdx.x;
  if (i >= NN * 32) return;
  out[i] = elu1(in[i] + b[i & 31]);
}

__global__ __launch_bounds__(256) void gconv2_kernel(const int* __restrict__ src,
                                                     const int* __restrict__ dst,
                                                     const float* __restrict__ xs,
                                                     float* __restrict__ c2) {
  int t = blockIdx.x * blockDim.x + threadIdx.x;
  int e = t >> 4, f = t & 15;
  if (e >= NE) return;
  atomicAdd(&c2[dst[e] * 16 + f], xs[src[e] * 16 + f]);
}

__global__ __launch_bounds__(256) void gconv2_post(const float* __restrict__ c2,
                                                   const float* __restrict__ cnt_in,
                                                   const float* __restrict__ b,
                                                   float* __restrict__ x4) {
  int i = blockIdx.x * blockDim.x + threadIdx.x;
  if (i >= NN * 16) return;
  int node = i >> 4;
  x4[i] = elu1(c2[i] * (1.f / sqrtf(fmaxf(cnt_in[node], 1.f))) + b[i & 15]);
}

// score[e, c] = concat(x4[src], x4[dst]) @ Wcls + bcls
__global__ __launch_bounds__(256) void classifier_kernel(const int* __restrict__ src,
                                                         const int* __restrict__ dst,
                                                         const float* __restrict__ x4,
                                                         const float* __restrict__ Wcls,
                                                         const float* __restrict__ bcls,
                                                         float* __restrict__ out) {
  __shared__ float w[256];
  __shared__ float bb[8];
  if (threadIdx.x < 256) w[threadIdx.x] = Wcls[threadIdx.x];
  if (threadIdx.x < 8) bb[threadIdx.x] = bcls[threadIdx.x];
  __syncthreads();
  int t = blockIdx.x * blockDim.x + threadIdx.x;
  int e = t >> 3, c = t & 7;
  if (e >= NE) return;
  int s = src[e], d = dst[e];
  float acc = bb[c];
#pragma unroll
  for (int f = 0; f < 16; ++f) acc += x4[s * 16 + f] * w[f * 8 + c];
#pragma unroll
  for (int f = 0; f < 16; ++f) acc += x4[d * 16 + f] * w[(16 + f) * 8 + c];
  out[e * 8 + c] = acc;
}

extern "C" void kernel_launch(void* const* d_in, const int* in_sizes, int n_in,
                              void* d_out, int out_size, void* d_ws, size_t ws_size,
                              hipStream_t stream) {
  const float* h      = (const float*)d_in[0];
  const float* edge_w = (const float*)d_in[1];
  const int*   src    = (const int*)d_in[2];
  const int*   dst    = (const int*)d_in[3];
  const float* Wn    = (const float*)d_in[4];
  const float* bn    = (const float*)d_in[5];
  const float* W1s   = (const float*)d_in[6];
  const float* b1s   = (const float*)d_in[7];
  const float* W1d   = (const float*)d_in[8];
  const float* b1d   = (const float*)d_in[9];
  const float* attn1 = (const float*)d_in[10];
  const float* W2s   = (const float*)d_in[11];
  const float* b2s   = (const float*)d_in[12];
  const float* W2d   = (const float*)d_in[13];
  const float* b2d   = (const float*)d_in[14];
  const float* attn2 = (const float*)d_in[15];
  const float* Wc1   = (const float*)d_in[16];
  const float* bc1   = (const float*)d_in[17];
  const float* Wc2   = (const float*)d_in[18];
  const float* bc2   = (const float*)d_in[19];
  const float* Wcls  = (const float*)d_in[20];
  const float* bcls  = (const float*)d_in[21];
  float* out = (float*)d_out;

  float* ws = (float*)d_ws;
  size_t off = 0;
  auto alloc = [&](size_t nf) { float* pp = ws + off; off += nf; return pp; };
  float* Wns = alloc(8192);
  float* Wnd = alloc(8192);
  float* bns = alloc(64);
  float* bnd = alloc(64);
  float* deg = alloc(4 * NN);   // wdeg_out | wdeg_in | cnt_out | cnt_in
  float* S   = alloc(2 * NN);   // softmax denominators (reused L1/L2); contiguous after deg
  float* FS  = alloc(64 * NN);  // fs1 -> fs2 -> c1(32N) + x3a(32N)
  float* FD  = alloc(64 * NN);  // fd1 -> fd2 -> xm(32N) + xs(16N)
  float* G   = alloc(64 * NN);  // g1 -> g2 -> c2(16N) + x4(16N)
  float* P   = alloc(2 * NE);   // per-edge exp(logit) (2 heads L1, 1 head L2)

  dim3 b256(256);
  const int ZB = 1024;

  combine_weights<<<65, b256, 0, stream>>>(Wn, bn, W1s, b1s, W1d, b1d, Wns, Wnd, bns, bnd);

  // deg(4N) + S(2N) are contiguous -> one zero pass; G zeroed in same launch
  zero2_kernel<<<ZB, b256, 0, stream>>>(deg, 6 * NN, G, 64 * NN);
  degrees_kernel<<<(NE + 255) / 256, b256, 0, stream>>>(edge_w, src, dst, deg);

  // layer 1 fs/fd directly from h (node_f linear folded in)
  node_gemm<128, 64, false, false><<<(NN + 3) / 4, b256, 0, stream>>>(h, Wns, bns, nullptr, FS);
  node_gemm<128, 64, false, false><<<(NN + 3) / 4, b256, 0, stream>>>(h, Wnd, bnd, nullptr, FD);

  gat1_logits<<<NE / 4, b256, 0, stream>>>(src, dst, FS, FD, attn1, P, S);
  gat1_agg<<<NE / 4, b256, 0, stream>>>(src, dst, FS, P, S, G);

  // layer 2 (elu fused into GEMM input read); G dead after these two reads
  node_gemm<64, 64, true, false><<<(NN + 3) / 4, b256, 0, stream>>>(G, W2s, b2s, nullptr, FS);
  node_gemm<64, 64, true, false><<<(NN + 3) / 4, b256, 0, stream>>>(G, W2d, b2d, nullptr, FD);
  zero2_kernel<<<ZB, b256, 0, stream>>>(S, 2 * NN, G, 64 * NN);
  gat2_logits<<<NE / 4, b256, 0, stream>>>(src, dst, FS, FD, attn2, P, S);
  gat2_agg<<<NE / 4, b256, 0, stream>>>(src, dst, FS, P, S, G);

  // GraphConv 1: xm = elu(g2) @ Wc1 ; c1 = segsum(xm[src]*norm_w) ; x3a = elu(c1+bc1)
  node_gemm<64, 32, true, false><<<(NN + 7) / 8, b256, 0, stream>>>(G, Wc1, nullptr, nullptr, FD);
  zero_kernel<<<ZB, b256, 0, stream>>>(FS, 32 * NN);
  gconv1_kernel<<<(NE * 32 + 255) / 256, b256, 0, stream>>>(src, dst, edge_w, deg, FD, FS);
  elu_bias32<<<(NN * 32 + 255) / 256, b256, 0, stream>>>(FS, bc1, FS + 32 * NN);

  // GraphConv 2: xs = (x3a @ Wc2)*rsqrt(dout) ; c2 = segsum(xs[src]) ; x4 = elu(c2*rsqrt(din)+bc2)
  node_gemm<32, 16, false, true><<<(NN + 15) / 16, b256, 0, stream>>>(FS + 32 * NN, Wc2, nullptr,
                                                                      deg + 2 * NN, FD + 32 * NN);
  zero_kernel<<<ZB, b256, 0, stream>>>(G, 16 * NN);
  gconv2_kernel<<<(NE * 16 + 255) / 256, b256, 0, stream>>>(src, dst, FD + 32 * NN, G);
  gconv2_post<<<(NN * 16 + 255) / 256, b256, 0, stream>>>(G, deg + 3 * NN, bc2, G + 16 * NN);

  classifier_kernel<<<(NE * 8 + 255) / 256, b256, 0, stream>>>(src, dst, G + 16 * NN, Wcls, bcls, out);
}

// Round 4
// 715.397 us; speedup vs baseline: 1.7536x; 1.7536x over previous
//
#include <hip/hip_runtime.h>
#include <math.h>

#define NN 50000
#define NE 800000
#define SCAN_BLOCKS ((NN + 255) / 256)  // 196

__device__ __forceinline__ float elu1(float x) { return x > 0.f ? x : expm1f(x); }
__device__ __forceinline__ float lrelu(float x) { return x >= 0.f ? x : 0.2f * x; }

__global__ __launch_bounds__(256) void zero_kernel(float* __restrict__ p, int n) {
  int i = blockIdx.x * blockDim.x + threadIdx.x;
  int stride = gridDim.x * blockDim.x;
  for (; i < n; i += stride) p[i] = 0.f;
}

// Fold node_f linear into layer-1 fs/fd linears:
//   Wns = Wn @ W1s, bns = bn @ W1s + b1s  (same for d)
__global__ __launch_bounds__(256) void combine_weights(
    const float* __restrict__ Wn, const float* __restrict__ bn,
    const float* __restrict__ W1s, const float* __restrict__ b1s,
    const float* __restrict__ W1d, const float* __restrict__ b1d,
    float* __restrict__ Wns, float* __restrict__ Wnd,
    float* __restrict__ bns, float* __restrict__ bnd) {
  int t = blockIdx.x * blockDim.x + threadIdx.x;
  if (t < 8192) {
    int i = t >> 6, o = t & 63;
    float acc = 0.f;
    for (int k = 0; k < 128; ++k) acc += Wn[i * 128 + k] * W1s[k * 64 + o];
    Wns[t] = acc;
  } else if (t < 16384) {
    int u = t - 8192;
    int i = u >> 6, o = u & 63;
    float acc = 0.f;
    for (int k = 0; k < 128; ++k) acc += Wn[i * 128 + k] * W1d[k * 64 + o];
    Wnd[u] = acc;
  } else if (t < 16448) {
    int o = t - 16384;
    float acc = b1s[o];
    for (int k = 0; k < 128; ++k) acc += bn[k] * W1s[k * 64 + o];
    bns[o] = acc;
  } else if (t < 16512) {
    int o = t - 16448;
    float acc = b1d[o];
    for (int k = 0; k < 128; ++k) acc += bn[k] * W1d[k * 64 + o];
    bnd[o] = acc;
  }
}

// src-side degrees (weighted + count) + dst histogram for CSR
__global__ __launch_bounds__(256) void edge_stats(const float* __restrict__ ew,
                                                  const int* __restrict__ src,
                                                  const int* __restrict__ dst,
                                                  float* __restrict__ deg,  // [0:N)=wdeg_out [N:2N)=cnt_out
                                                  int* __restrict__ cnt) {  // dst histogram
  int e = blockIdx.x * blockDim.x + threadIdx.x;
  if (e >= NE) return;
  int s = src[e], d = dst[e];
  atomicAdd(&deg[s], ew[e]);
  atomicAdd(&deg[NN + s], 1.f);
  atomicAdd(&cnt[d], 1);
}

__global__ __launch_bounds__(256) void csr_block_sums(const int* __restrict__ cnt,
                                                      int* __restrict__ part) {
  __shared__ int sh[256];
  int i = blockIdx.x * 256 + threadIdx.x;
  sh[threadIdx.x] = (i < NN) ? cnt[i] : 0;
  __syncthreads();
  for (int s = 128; s > 0; s >>= 1) {
    if (threadIdx.x < s) sh[threadIdx.x] += sh[threadIdx.x + s];
    __syncthreads();
  }
  if (threadIdx.x == 0) part[blockIdx.x] = sh[0];
}

__global__ __launch_bounds__(256) void csr_scan_part(int* __restrict__ part) {
  __shared__ int sh[256];
  int t = threadIdx.x;
  int v = (t < SCAN_BLOCKS) ? part[t] : 0;
  sh[t] = v;
  __syncthreads();
  for (int off = 1; off < 256; off <<= 1) {
    int add = (t >= off) ? sh[t - off] : 0;
    __syncthreads();
    sh[t] += add;
    __syncthreads();
  }
  if (t < SCAN_BLOCKS) part[t] = sh[t] - v;  // exclusive
}

__global__ __launch_bounds__(256) void csr_scan_write(const int* __restrict__ cnt,
                                                      const int* __restrict__ part,
                                                      int* __restrict__ row_start) {
  __shared__ int sh[256];
  int i = blockIdx.x * 256 + threadIdx.x;
  int t = threadIdx.x;
  int v = (i < NN) ? cnt[i] : 0;
  sh[t] = v;
  __syncthreads();
  for (int off = 1; off < 256; off <<= 1) {
    int add = (t >= off) ? sh[t - off] : 0;
    __syncthreads();
    sh[t] += add;
    __syncthreads();
  }
  if (i < NN) row_start[i] = part[blockIdx.x] + sh[t] - v;
  if (i == 0) row_start[NN] = NE;
}

// scatter edges into dst-sorted order; store permuted src and weight
__global__ __launch_bounds__(256) void csr_fill(const int* __restrict__ src,
                                                const int* __restrict__ dst,
                                                const float* __restrict__ ew,
                                                const int* __restrict__ row_start,
                                                int* __restrict__ fill,
                                                int* __restrict__ psrc,
                                                float* __restrict__ pw) {
  int e = blockIdx.x * blockDim.x + threadIdx.x;
  if (e >= NE) return;
  int d = dst[e];
  int pos = row_start[d] + atomicAdd(&fill[d], 1);
  psrc[pos] = src[e];
  pw[pos] = ew[e];
}

// Y[N,M] = (ELU_IN? elu(X) : X)[N,K] @ W[K,M] (+b) (* rsqrt(max(cnt,1)) if RS_OUT)
template <int K, int M, bool ELU_IN, bool RS_OUT>
__global__ __launch_bounds__(256) void node_gemm(const float* __restrict__ X,
                                                 const float* __restrict__ W,
                                                 const float* __restrict__ b,
                                                 const float* __restrict__ cnt,
                                                 float* __restrict__ Y) {
  constexpr int ROWS = 256 / M;
  __shared__ float xs[ROWS][K];
  int row0 = blockIdx.x * ROWS;
  int t = threadIdx.x;
  for (int idx = t; idx < ROWS * K; idx += 256) {
    int r = idx / K, k = idx - r * K;
    int row = row0 + r;
    float v = (row < NN) ? X[row * K + k] : 0.f;
    if (ELU_IN) v = elu1(v);
    xs[r][k] = v;
  }
  __syncthreads();
  int r = t / M, m = t - (t / M) * M;
  int row = row0 + r;
  if (row >= NN) return;
  float acc = b ? b[m] : 0.f;
#pragma unroll
  for (int k = 0; k < K; ++k) acc += xs[r][k] * W[k * M + m];
  if (RS_OUT) acc *= rsqrtf(fmaxf(cnt[row], 1.f));
  Y[row * M + m] = acc;
}

// Fused GATv2 layer: per dst node, single pass over in-edges; 2-way unrolled for ILP.
// HALFW: 1 -> reduce over 32-lane halves (2 heads x 32), 0 -> full 64 (1 head x 64)
template <int HALFW>
__global__ __launch_bounds__(256) void gat_fused(const int* __restrict__ row_start,
                                                 const int* __restrict__ psrc,
                                                 const float* __restrict__ fs,
                                                 const float* __restrict__ fd,
                                                 const float* __restrict__ attn,
                                                 float* __restrict__ g) {
  int n = blockIdx.x * 4 + (threadIdx.x >> 6);
  if (n >= NN) return;
  int lane = threadIdx.x & 63;
  int beg = row_start[n], end = row_start[n + 1];
  float fdv = fd[n * 64 + lane];
  float av = attn[lane];
  float acc = 0.f, den = 0.f;
  int i = beg;
  for (; i + 1 < end; i += 2) {
    int s0 = psrc[i], s1 = psrc[i + 1];
    float f0 = fs[s0 * 64 + lane];
    float f1 = fs[s1 * 64 + lane];
    float v0 = lrelu(f0 + fdv) * av;
    float v1 = lrelu(f1 + fdv) * av;
#pragma unroll
    for (int m = 16; m >= 1; m >>= 1) {
      v0 += __shfl_xor(v0, m, 64);
      v1 += __shfl_xor(v1, m, 64);
    }
    if (!HALFW) {
      v0 += __shfl_xor(v0, 32, 64);
      v1 += __shfl_xor(v1, 32, 64);
    }
    float p0 = __expf(v0);  // softmax shift-invariant; logits tiny -> no max pass
    float p1 = __expf(v1);
    acc += f0 * p0 + f1 * p1;
    den += p0 + p1;
  }
  if (i < end) {
    int s = psrc[i];
    float fsv = fs[s * 64 + lane];
    float v = lrelu(fsv + fdv) * av;
#pragma unroll
    for (int m = 16; m >= 1; m >>= 1) v += __shfl_xor(v, m, 64);
    if (!HALFW) v += __shfl_xor(v, 32, 64);
    float p = __expf(v);
    acc += fsv * p;
    den += p;
  }
  g[n * 64 + lane] = (end > beg) ? acc / den : 0.f;
}

// Fused GraphConv1: c1[n] = rsqrt(inw[n]) * sum_e pw*rsqrt(outw[src])*xm[src]; out = elu(c1+bc1)
// inw computed on the fly as sum of pw over the row. 2 edges per wave iteration (32 feats each).
__global__ __launch_bounds__(256) void gconv1_fused(const int* __restrict__ row_start,
                                                    const int* __restrict__ psrc,
                                                    const float* __restrict__ pw,
                                                    const float* __restrict__ outw,
                                                    const float* __restrict__ xm,
                                                    const float* __restrict__ bc1,
                                                    float* __restrict__ x3a) {
  int n = blockIdx.x * 4 + (threadIdx.x >> 6);
  if (n >= NN) return;
  int lane = threadIdx.x & 63;
  int half = lane >> 5, f = lane & 31;
  int beg = row_start[n], end = row_start[n + 1];
  float acc = 0.f, wsum = 0.f;
  for (int i = beg + half; i < end; i += 2) {
    int s = psrc[i];
    float w = pw[i];
    acc += xm[s * 32 + f] * (w * rsqrtf(outw[s]));
    wsum += w;
  }
  acc += __shfl_xor(acc, 32, 64);
  wsum += __shfl_xor(wsum, 32, 64);
  if (lane < 32) {
    float r = (end > beg) ? acc * rsqrtf(wsum) : 0.f;
    x3a[n * 32 + lane] = elu1(r + bc1[lane]);
  }
}

// Fused GraphConv2: x4[n] = elu( rsqrt(max(len,1)) * sum_e xs[src] + bc2 ). 4 edges/iter (16 feats).
__global__ __launch_bounds__(256) void gconv2_fused(const int* __restrict__ row_start,
                                                    const int* __restrict__ psrc,
                                                    const float* __restrict__ xs,
                                                    const float* __restrict__ bc2,
                                                    float* __restrict__ x4) {
  int n = blockIdx.x * 4 + (threadIdx.x >> 6);
  if (n >= NN) return;
  int lane = threadIdx.x & 63;
  int q = lane >> 4, f = lane & 15;
  int beg = row_start[n], end = row_start[n + 1];
  float acc = 0.f;
  for (int i = beg + q; i < end; i += 4) acc += xs[psrc[i] * 16 + f];
  acc += __shfl_xor(acc, 16, 64);
  acc += __shfl_xor(acc, 32, 64);
  if (lane < 16) {
    float len = (float)(end - beg);
    x4[n * 16 + lane] = elu1(acc * rsqrtf(fmaxf(len, 1.f)) + bc2[lane]);
  }
}

// score[e, c] = concat(x4[src], x4[dst]) @ Wcls + bcls
__global__ __launch_bounds__(256) void classifier_kernel(const int* __restrict__ src,
                                                         const int* __restrict__ dst,
                                                         const float* __restrict__ x4,
                                                         const float* __restrict__ Wcls,
                                                         const float* __restrict__ bcls,
                                                         float* __restrict__ out) {
  __shared__ float w[256];
  __shared__ float bb[8];
  if (threadIdx.x < 256) w[threadIdx.x] = Wcls[threadIdx.x];
  if (threadIdx.x < 8) bb[threadIdx.x] = bcls[threadIdx.x];
  __syncthreads();
  int t = blockIdx.x * blockDim.x + threadIdx.x;
  int e = t >> 3, c = t & 7;
  if (e >= NE) return;
  int s = src[e], d = dst[e];
  float acc = bb[c];
#pragma unroll
  for (int f = 0; f < 16; ++f) acc += x4[s * 16 + f] * w[f * 8 + c];
#pragma unroll
  for (int f = 0; f < 16; ++f) acc += x4[d * 16 + f] * w[(16 + f) * 8 + c];
  out[e * 8 + c] = acc;
}

extern "C" void kernel_launch(void* const* d_in, const int* in_sizes, int n_in,
                              void* d_out, int out_size, void* d_ws, size_t ws_size,
                              hipStream_t stream) {
  const float* h      = (const float*)d_in[0];
  const float* edge_w = (const float*)d_in[1];
  const int*   src    = (const int*)d_in[2];
  const int*   dst    = (const int*)d_in[3];
  const float* Wn    = (const float*)d_in[4];
  const float* bn    = (const float*)d_in[5];
  const float* W1s   = (const float*)d_in[6];
  const float* b1s   = (const float*)d_in[7];
  const float* W1d   = (const float*)d_in[8];
  const float* b1d   = (const float*)d_in[9];
  const float* attn1 = (const float*)d_in[10];
  const float* W2s   = (const float*)d_in[11];
  const float* b2s   = (const float*)d_in[12];
  const float* W2d   = (const float*)d_in[13];
  const float* b2d   = (const float*)d_in[14];
  const float* attn2 = (const float*)d_in[15];
  const float* Wc1   = (const float*)d_in[16];
  const float* bc1   = (const float*)d_in[17];
  const float* Wc2   = (const float*)d_in[18];
  const float* bc2   = (const float*)d_in[19];
  const float* Wcls  = (const float*)d_in[20];
  const float* bcls  = (const float*)d_in[21];
  float* out = (float*)d_out;

  float* ws = (float*)d_ws;
  size_t off = 0;
  auto alloc = [&](size_t nf) { float* pp = ws + off; off += nf; return pp; };
  float* Wns = alloc(8192);
  float* Wnd = alloc(8192);
  float* bns = alloc(64);
  float* bnd = alloc(64);
  float* deg = alloc(2 * NN);          // wdeg_out | cnt_out
  int*   cnt = (int*)alloc(NN);        // dst histogram (contiguous with deg for one zero pass)
  int*   fillp = (int*)alloc(NN);      // csr fill cursors
  int*   row_start = (int*)alloc(NN + 1);
  int*   part = (int*)alloc(256);      // scan partials
  int*   psrc = (int*)alloc(NE);       // dst-sorted src ids
  float* pw   = alloc(NE);             // dst-sorted edge weights
  float* FS  = alloc(64 * NN);         // fs1 -> fs2 -> xm(32N) -> xs(16N)
  float* FD  = alloc(64 * NN);         // fd1 -> fd2 -> x3a(32N)
  float* G   = alloc(64 * NN);         // g1 -> g2 -> x4(16N)

  dim3 b256(256);
  const int EB = (NE + 255) / 256;
  const int NB4 = (NN + 3) / 4;

  combine_weights<<<65, b256, 0, stream>>>(Wn, bn, W1s, b1s, W1d, b1d, Wns, Wnd, bns, bnd);

  // deg(2N) + cnt(N) + fill(N) contiguous -> one zero pass
  zero_kernel<<<1024, b256, 0, stream>>>(deg, 4 * NN);
  edge_stats<<<EB, b256, 0, stream>>>(edge_w, src, dst, deg, cnt);

  // CSR build (dst-sorted)
  csr_block_sums<<<SCAN_BLOCKS, b256, 0, stream>>>(cnt, part);
  csr_scan_part<<<1, b256, 0, stream>>>(part);
  csr_scan_write<<<SCAN_BLOCKS, b256, 0, stream>>>(cnt, part, row_start);
  csr_fill<<<EB, b256, 0, stream>>>(src, dst, edge_w, row_start, fillp, psrc, pw);

  // layer 1 fs/fd directly from h (node_f linear folded in)
  node_gemm<128, 64, false, false><<<NB4, b256, 0, stream>>>(h, Wns, bns, nullptr, FS);
  node_gemm<128, 64, false, false><<<NB4, b256, 0, stream>>>(h, Wnd, bnd, nullptr, FD);
  gat_fused<1><<<NB4, b256, 0, stream>>>(row_start, psrc, FS, FD, attn1, G);

  // layer 2 (elu fused into GEMM input read); G dead after these two reads
  node_gemm<64, 64, true, false><<<NB4, b256, 0, stream>>>(G, W2s, b2s, nullptr, FS);
  node_gemm<64, 64, true, false><<<NB4, b256, 0, stream>>>(G, W2d, b2d, nullptr, FD);
  gat_fused<0><<<NB4, b256, 0, stream>>>(row_start, psrc, FS, FD, attn2, G);

  // GraphConv 1: xm = elu(g2) @ Wc1 ; x3a = elu(rsqrt(inw)*sum(pw*rsqrt(outw)*xm[src]) + bc1)
  node_gemm<64, 32, true, false><<<(NN + 7) / 8, b256, 0, stream>>>(G, Wc1, nullptr, nullptr, FS);
  gconv1_fused<<<NB4, b256, 0, stream>>>(row_start, psrc, pw, deg, FS, bc1, FD);

  // GraphConv 2: xs = (x3a @ Wc2)*rsqrt(dout) ; x4 = elu(rsqrt(din)*sum(xs[src]) + bc2)
  node_gemm<32, 16, false, true><<<(NN + 15) / 16, b256, 0, stream>>>(FD, Wc2, nullptr,
                                                                      deg + NN, FS);
  gconv2_fused<<<NB4, b256, 0, stream>>>(row_start, psrc, FS, bc2, G);

  classifier_kernel<<<(NE * 8 + 255) / 256, b256, 0, stream>>>(src, dst, G, Wcls, bcls, out);
}

// Round 5
// 660.858 us; speedup vs baseline: 1.8983x; 1.0825x over previous
//
#include <hip/hip_runtime.h>
#include <math.h>

#define NN 50000
#define NE 800000
#define SCAN_BLOCKS ((NN + 255) / 256)  // 196

__device__ __forceinline__ float elu1(float x) { return x > 0.f ? x : expm1f(x); }
__device__ __forceinline__ float lrelu(float x) { return x >= 0.f ? x : 0.2f * x; }

__global__ __launch_bounds__(256) void zero_kernel(float* __restrict__ p, int n) {
  int i = blockIdx.x * blockDim.x + threadIdx.x;
  int stride = gridDim.x * blockDim.x;
  for (; i < n; i += stride) p[i] = 0.f;
}

// Fold node_f linear into layer-1 fs/fd linears:
//   Wns = Wn @ W1s, bns = bn @ W1s + b1s  (same for d)
__global__ __launch_bounds__(256) void combine_weights(
    const float* __restrict__ Wn, const float* __restrict__ bn,
    const float* __restrict__ W1s, const float* __restrict__ b1s,
    const float* __restrict__ W1d, const float* __restrict__ b1d,
    float* __restrict__ Wns, float* __restrict__ Wnd,
    float* __restrict__ bns, float* __restrict__ bnd) {
  int t = blockIdx.x * blockDim.x + threadIdx.x;
  if (t < 8192) {
    int i = t >> 6, o = t & 63;
    float acc = 0.f;
    for (int k = 0; k < 128; ++k) acc += Wn[i * 128 + k] * W1s[k * 64 + o];
    Wns[t] = acc;
  } else if (t < 16384) {
    int u = t - 8192;
    int i = u >> 6, o = u & 63;
    float acc = 0.f;
    for (int k = 0; k < 128; ++k) acc += Wn[i * 128 + k] * W1d[k * 64 + o];
    Wnd[u] = acc;
  } else if (t < 16448) {
    int o = t - 16384;
    float acc = b1s[o];
    for (int k = 0; k < 128; ++k) acc += bn[k] * W1s[k * 64 + o];
    bns[o] = acc;
  } else if (t < 16512) {
    int o = t - 16448;
    float acc = b1d[o];
    for (int k = 0; k < 128; ++k) acc += bn[k] * W1d[k * 64 + o];
    bnd[o] = acc;
  }
}

// src-side degrees packed in ONE u64 atomic per edge:
//   bits [44:64) = out-edge count, bits [0:44) = sum(w * 2^32) fixed-point.
// Plus dst histogram (u32) for the CSR build. 2 atomics/edge total (was 3).
__global__ __launch_bounds__(256) void edge_stats(const float* __restrict__ ew,
                                                  const int* __restrict__ src,
                                                  const int* __restrict__ dst,
                                                  unsigned long long* __restrict__ degw,
                                                  int* __restrict__ cnt) {
  int e = blockIdx.x * blockDim.x + threadIdx.x;
  if (e >= NE) return;
  int s = src[e], d = dst[e];
  unsigned long long pk = (1ULL << 44) | (unsigned long long)(ew[e] * 4294967296.0f);
  atomicAdd(&degw[s], pk);
  atomicAdd(&cnt[d], 1);
}

// unpack degw -> deg[0:N)=wdeg_out (float), deg[N:2N)=cnt_out (float)
__global__ __launch_bounds__(256) void decode_degrees(const unsigned long long* __restrict__ degw,
                                                      float* __restrict__ deg) {
  int i = blockIdx.x * blockDim.x + threadIdx.x;
  if (i >= NN) return;
  unsigned long long v = degw[i];
  deg[i] = (float)((double)(v & ((1ULL << 44) - 1)) * (1.0 / 4294967296.0));
  deg[NN + i] = (float)(v >> 44);
}

__global__ __launch_bounds__(256) void csr_block_sums(const int* __restrict__ cnt,
                                                      int* __restrict__ part) {
  __shared__ int sh[256];
  int i = blockIdx.x * 256 + threadIdx.x;
  sh[threadIdx.x] = (i < NN) ? cnt[i] : 0;
  __syncthreads();
  for (int s = 128; s > 0; s >>= 1) {
    if (threadIdx.x < s) sh[threadIdx.x] += sh[threadIdx.x + s];
    __syncthreads();
  }
  if (threadIdx.x == 0) part[blockIdx.x] = sh[0];
}

__global__ __launch_bounds__(256) void csr_scan_part(int* __restrict__ part) {
  __shared__ int sh[256];
  int t = threadIdx.x;
  int v = (t < SCAN_BLOCKS) ? part[t] : 0;
  sh[t] = v;
  __syncthreads();
  for (int off = 1; off < 256; off <<= 1) {
    int add = (t >= off) ? sh[t - off] : 0;
    __syncthreads();
    sh[t] += add;
    __syncthreads();
  }
  if (t < SCAN_BLOCKS) part[t] = sh[t] - v;  // exclusive
}

__global__ __launch_bounds__(256) void csr_scan_write(const int* __restrict__ cnt,
                                                      const int* __restrict__ part,
                                                      int* __restrict__ row_start) {
  __shared__ int sh[256];
  int i = blockIdx.x * 256 + threadIdx.x;
  int t = threadIdx.x;
  int v = (i < NN) ? cnt[i] : 0;
  sh[t] = v;
  __syncthreads();
  for (int off = 1; off < 256; off <<= 1) {
    int add = (t >= off) ? sh[t - off] : 0;
    __syncthreads();
    sh[t] += add;
    __syncthreads();
  }
  if (i < NN) row_start[i] = part[blockIdx.x] + sh[t] - v;
  if (i == 0) row_start[NN] = NE;
}

// scatter edges into dst-sorted order; ONE 8B store per edge: (src, weight_bits)
__global__ __launch_bounds__(256) void csr_fill(const int* __restrict__ src,
                                                const int* __restrict__ dst,
                                                const float* __restrict__ ew,
                                                const int* __restrict__ row_start,
                                                int* __restrict__ fill,
                                                int2* __restrict__ psrcw) {
  int e = blockIdx.x * blockDim.x + threadIdx.x;
  if (e >= NE) return;
  int d = dst[e];
  int pos = row_start[d] + atomicAdd(&fill[d], 1);
  psrcw[pos] = make_int2(src[e], __float_as_int(ew[e]));
}

// Y[N,M] = (ELU_IN? elu(X) : X)[N,K] @ W[K,M] (+b), then:
//   RS=1: *= rsqrt(max(cnt,1))   (clamped count norm)
//   RS=2: *= cnt>0 ? rsqrt(cnt) : 0   (raw weighted-degree norm, guarded)
template <int K, int M, bool ELU_IN, int RS>
__global__ __launch_bounds__(256) void node_gemm(const float* __restrict__ X,
                                                 const float* __restrict__ W,
                                                 const float* __restrict__ b,
                                                 const float* __restrict__ cnt,
                                                 float* __restrict__ Y) {
  constexpr int ROWS = 256 / M;
  __shared__ float xs[ROWS][K];
  int row0 = blockIdx.x * ROWS;
  int t = threadIdx.x;
  for (int idx = t; idx < ROWS * K; idx += 256) {
    int r = idx / K, k = idx - r * K;
    int row = row0 + r;
    float v = (row < NN) ? X[row * K + k] : 0.f;
    if (ELU_IN) v = elu1(v);
    xs[r][k] = v;
  }
  __syncthreads();
  int r = t / M, m = t - (t / M) * M;
  int row = row0 + r;
  if (row >= NN) return;
  float acc = b ? b[m] : 0.f;
#pragma unroll
  for (int k = 0; k < K; ++k) acc += xs[r][k] * W[k * M + m];
  if (RS == 1) acc *= rsqrtf(fmaxf(cnt[row], 1.f));
  if (RS == 2) {
    float wv = cnt[row];
    acc *= (wv > 0.f) ? rsqrtf(wv) : 0.f;
  }
  Y[row * M + m] = acc;
}

// Fused GATv2 layer: per dst node, single pass over in-edges; 2-way unrolled for ILP.
// HALFW: 1 -> reduce over 32-lane halves (2 heads x 32), 0 -> full 64 (1 head x 64)
template <int HALFW>
__global__ __launch_bounds__(256) void gat_fused(const int* __restrict__ row_start,
                                                 const int2* __restrict__ psrcw,
                                                 const float* __restrict__ fs,
                                                 const float* __restrict__ fd,
                                                 const float* __restrict__ attn,
                                                 float* __restrict__ g) {
  int n = blockIdx.x * 4 + (threadIdx.x >> 6);
  if (n >= NN) return;
  int lane = threadIdx.x & 63;
  int beg = row_start[n], end = row_start[n + 1];
  float fdv = fd[n * 64 + lane];
  float av = attn[lane];
  float acc = 0.f, den = 0.f;
  int i = beg;
  for (; i + 1 < end; i += 2) {
    int s0 = psrcw[i].x, s1 = psrcw[i + 1].x;
    float f0 = fs[s0 * 64 + lane];
    float f1 = fs[s1 * 64 + lane];
    float v0 = lrelu(f0 + fdv) * av;
    float v1 = lrelu(f1 + fdv) * av;
#pragma unroll
    for (int m = 16; m >= 1; m >>= 1) {
      v0 += __shfl_xor(v0, m, 64);
      v1 += __shfl_xor(v1, m, 64);
    }
    if (!HALFW) {
      v0 += __shfl_xor(v0, 32, 64);
      v1 += __shfl_xor(v1, 32, 64);
    }
    float p0 = __expf(v0);  // softmax shift-invariant; logits tiny -> no max pass
    float p1 = __expf(v1);
    acc += f0 * p0 + f1 * p1;
    den += p0 + p1;
  }
  if (i < end) {
    int s = psrcw[i].x;
    float fsv = fs[s * 64 + lane];
    float v = lrelu(fsv + fdv) * av;
#pragma unroll
    for (int m = 16; m >= 1; m >>= 1) v += __shfl_xor(v, m, 64);
    if (!HALFW) v += __shfl_xor(v, 32, 64);
    float p = __expf(v);
    acc += fsv * p;
    den += p;
  }
  g[n * 64 + lane] = (end > beg) ? acc / den : 0.f;
}

// Fused GraphConv1: x3a[n] = elu( rsqrt(inw[n]) * sum_e w_e * ym[src_e] + bc1 )
// where ym already carries rsqrt(outw[src]) (folded into the GEMM).
// inw computed on the fly as sum of w over the row. 2 edges per wave iteration (32 feats each).
__global__ __launch_bounds__(256) void gconv1_fused(const int* __restrict__ row_start,
                                                    const int2* __restrict__ psrcw,
                                                    const float* __restrict__ ym,
                                                    const float* __restrict__ bc1,
                                                    float* __restrict__ x3a) {
  int n = blockIdx.x * 4 + (threadIdx.x >> 6);
  if (n >= NN) return;
  int lane = threadIdx.x & 63;
  int half = lane >> 5, f = lane & 31;
  int beg = row_start[n], end = row_start[n + 1];
  float acc = 0.f, wsum = 0.f;
  for (int i = beg + half; i < end; i += 2) {
    int2 pr = psrcw[i];
    float w = __int_as_float(pr.y);
    acc += ym[pr.x * 32 + f] * w;
    wsum += w;
  }
  acc += __shfl_xor(acc, 32, 64);
  wsum += __shfl_xor(wsum, 32, 64);
  if (lane < 32) {
    float r = (end > beg) ? acc * rsqrtf(wsum) : 0.f;
    x3a[n * 32 + lane] = elu1(r + bc1[lane]);
  }
}

// Fused GraphConv2: x4[n] = elu( rsqrt(max(len,1)) * sum_e xs[src] + bc2 ). 4 edges/iter (16 feats).
__global__ __launch_bounds__(256) void gconv2_fused(const int* __restrict__ row_start,
                                                    const int2* __restrict__ psrcw,
                                                    const float* __restrict__ xs,
                                                    const float* __restrict__ bc2,
                                                    float* __restrict__ x4) {
  int n = blockIdx.x * 4 + (threadIdx.x >> 6);
  if (n >= NN) return;
  int lane = threadIdx.x & 63;
  int q = lane >> 4, f = lane & 15;
  int beg = row_start[n], end = row_start[n + 1];
  float acc = 0.f;
  for (int i = beg + q; i < end; i += 4) acc += xs[psrcw[i].x * 16 + f];
  acc += __shfl_xor(acc, 16, 64);
  acc += __shfl_xor(acc, 32, 64);
  if (lane < 16) {
    float len = (float)(end - beg);
    x4[n * 16 + lane] = elu1(acc * rsqrtf(fmaxf(len, 1.f)) + bc2[lane]);
  }
}

// score[e, c] = concat(x4[src], x4[dst]) @ Wcls + bcls
__global__ __launch_bounds__(256) void classifier_kernel(const int* __restrict__ src,
                                                         const int* __restrict__ dst,
                                                         const float* __restrict__ x4,
                                                         const float* __restrict__ Wcls,
                                                         const float* __restrict__ bcls,
                                                         float* __restrict__ out) {
  __shared__ float w[256];
  __shared__ float bb[8];
  if (threadIdx.x < 256) w[threadIdx.x] = Wcls[threadIdx.x];
  if (threadIdx.x < 8) bb[threadIdx.x] = bcls[threadIdx.x];
  __syncthreads();
  int t = blockIdx.x * blockDim.x + threadIdx.x;
  int e = t >> 3, c = t & 7;
  if (e >= NE) return;
  int s = src[e], d = dst[e];
  float acc = bb[c];
#pragma unroll
  for (int f = 0; f < 16; ++f) acc += x4[s * 16 + f] * w[f * 8 + c];
#pragma unroll
  for (int f = 0; f < 16; ++f) acc += x4[d * 16 + f] * w[(16 + f) * 8 + c];
  out[e * 8 + c] = acc;
}

extern "C" void kernel_launch(void* const* d_in, const int* in_sizes, int n_in,
                              void* d_out, int out_size, void* d_ws, size_t ws_size,
                              hipStream_t stream) {
  const float* h      = (const float*)d_in[0];
  const float* edge_w = (const float*)d_in[1];
  const int*   src    = (const int*)d_in[2];
  const int*   dst    = (const int*)d_in[3];
  const float* Wn    = (const float*)d_in[4];
  const float* bn    = (const float*)d_in[5];
  const float* W1s   = (const float*)d_in[6];
  const float* b1s   = (const float*)d_in[7];
  const float* W1d   = (const float*)d_in[8];
  const float* b1d   = (const float*)d_in[9];
  const float* attn1 = (const float*)d_in[10];
  const float* W2s   = (const float*)d_in[11];
  const float* b2s   = (const float*)d_in[12];
  const float* W2d   = (const float*)d_in[13];
  const float* b2d   = (const float*)d_in[14];
  const float* attn2 = (const float*)d_in[15];
  const float* Wc1   = (const float*)d_in[16];
  const float* bc1   = (const float*)d_in[17];
  const float* Wc2   = (const float*)d_in[18];
  const float* bc2   = (const float*)d_in[19];
  const float* Wcls  = (const float*)d_in[20];
  const float* bcls  = (const float*)d_in[21];
  float* out = (float*)d_out;

  float* ws = (float*)d_ws;
  size_t off = 0;
  auto alloc = [&](size_t nf) { float* pp = ws + off; off += nf; return pp; };
  float* Wns = alloc(8192);
  float* Wnd = alloc(8192);
  float* bns = alloc(64);
  float* bnd = alloc(64);
  // zero region: degw(2N words) | cnt(N) | fill(N)  -> 4N words, contiguous
  unsigned long long* degw = (unsigned long long*)alloc(2 * NN);
  int*   cnt = (int*)alloc(NN);
  int*   fillp = (int*)alloc(NN);
  float* deg = alloc(2 * NN);          // decoded: wdeg_out | cnt_out (written fully by decode)
  int*   row_start = (int*)alloc(NN + 1);
  int*   part = (int*)alloc(256);      // scan partials
  int2*  psrcw = (int2*)alloc(2 * NE); // dst-sorted (src, weight_bits) pairs
  float* FS  = alloc(64 * NN);         // fs1 -> fs2 -> ym(32N) -> xs(16N)
  float* FD  = alloc(64 * NN);         // fd1 -> fd2 -> x3a(32N)
  float* G   = alloc(64 * NN);         // g1 -> g2 -> x4(16N)

  dim3 b256(256);
  const int EB = (NE + 255) / 256;
  const int NB4 = (NN + 3) / 4;

  combine_weights<<<65, b256, 0, stream>>>(Wn, bn, W1s, b1s, W1d, b1d, Wns, Wnd, bns, bnd);

  zero_kernel<<<1024, b256, 0, stream>>>((float*)degw, 4 * NN);
  edge_stats<<<EB, b256, 0, stream>>>(edge_w, src, dst, degw, cnt);
  decode_degrees<<<SCAN_BLOCKS, b256, 0, stream>>>(degw, deg);

  // CSR build (dst-sorted)
  csr_block_sums<<<SCAN_BLOCKS, b256, 0, stream>>>(cnt, part);
  csr_scan_part<<<1, b256, 0, stream>>>(part);
  csr_scan_write<<<SCAN_BLOCKS, b256, 0, stream>>>(cnt, part, row_start);
  csr_fill<<<EB, b256, 0, stream>>>(src, dst, edge_w, row_start, fillp, psrcw);

  // layer 1 fs/fd directly from h (node_f linear folded in)
  node_gemm<128, 64, false, 0><<<NB4, b256, 0, stream>>>(h, Wns, bns, nullptr, FS);
  node_gemm<128, 64, false, 0><<<NB4, b256, 0, stream>>>(h, Wnd, bnd, nullptr, FD);
  gat_fused<1><<<NB4, b256, 0, stream>>>(row_start, psrcw, FS, FD, attn1, G);

  // layer 2 (elu fused into GEMM input read); G dead after these two reads
  node_gemm<64, 64, true, 0><<<NB4, b256, 0, stream>>>(G, W2s, b2s, nullptr, FS);
  node_gemm<64, 64, true, 0><<<NB4, b256, 0, stream>>>(G, W2d, b2d, nullptr, FD);
  gat_fused<0><<<NB4, b256, 0, stream>>>(row_start, psrcw, FS, FD, attn2, G);

  // GraphConv 1: ym = elu(g2) @ Wc1 * rsqrt(outw)  (norm folded into GEMM);
  //              x3a = elu(rsqrt(inw)*sum(w*ym[src]) + bc1)
  node_gemm<64, 32, true, 2><<<(NN + 7) / 8, b256, 0, stream>>>(G, Wc1, nullptr, deg, FS);
  gconv1_fused<<<NB4, b256, 0, stream>>>(row_start, psrcw, FS, bc1, FD);

  // GraphConv 2: xs = (x3a @ Wc2)*rsqrt(max(dout,1)) ; x4 = elu(rsqrt(din)*sum(xs[src]) + bc2)
  node_gemm<32, 16, false, 1><<<(NN + 15) / 16, b256, 0, stream>>>(FD, Wc2, nullptr,
                                                                   deg + NN, FS);
  gconv2_fused<<<NB4, b256, 0, stream>>>(row_start, psrcw, FS, bc2, G);

  classifier_kernel<<<(NE * 8 + 255) / 256, b256, 0, stream>>>(src, dst, G, Wcls, bcls, out);
}

// Round 7
// 535.145 us; speedup vs baseline: 2.3442x; 1.2349x over previous
//
#include <hip/hip_runtime.h>
#include <math.h>

#define NN 50000
#define NE 800000
#define SCAN_BLOCKS ((NN + 255) / 256)  // 196

__device__ __forceinline__ float elu1(float x) { return x > 0.f ? x : expm1f(x); }
__device__ __forceinline__ float lrelu(float x) { return x >= 0.f ? x : 0.2f * x; }

__global__ __launch_bounds__(256) void zero_kernel(float* __restrict__ p, int n) {
  int i = blockIdx.x * blockDim.x + threadIdx.x;
  int stride = gridDim.x * blockDim.x;
  for (; i < n; i += stride) p[i] = 0.f;
}

// Fold node_f linear into layer-1 fs/fd linears:
//   Wns = Wn @ W1s, bns = bn @ W1s + b1s  (same for d)
__global__ __launch_bounds__(256) void combine_weights(
    const float* __restrict__ Wn, const float* __restrict__ bn,
    const float* __restrict__ W1s, const float* __restrict__ b1s,
    const float* __restrict__ W1d, const float* __restrict__ b1d,
    float* __restrict__ Wns, float* __restrict__ Wnd,
    float* __restrict__ bns, float* __restrict__ bnd) {
  int t = blockIdx.x * blockDim.x + threadIdx.x;
  if (t < 8192) {
    int i = t >> 6, o = t & 63;
    float acc = 0.f;
    for (int k = 0; k < 128; ++k) acc += Wn[i * 128 + k] * W1s[k * 64 + o];
    Wns[t] = acc;
  } else if (t < 16384) {
    int u = t - 8192;
    int i = u >> 6, o = u & 63;
    float acc = 0.f;
    for (int k = 0; k < 128; ++k) acc += Wn[i * 128 + k] * W1d[k * 64 + o];
    Wnd[u] = acc;
  } else if (t < 16448) {
    int o = t - 16384;
    float acc = b1s[o];
    for (int k = 0; k < 128; ++k) acc += bn[k] * W1s[k * 64 + o];
    bns[o] = acc;
  } else if (t < 16512) {
    int o = t - 16448;
    float acc = b1d[o];
    for (int k = 0; k < 128; ++k) acc += bn[k] * W1d[k * 64 + o];
    bnd[o] = acc;
  }
}

// src-side degrees packed in ONE u64 atomic per edge:
//   bits [44:64) = out-edge count, bits [0:44) = sum(w * 2^32) fixed-point.
// Plus dst histogram (u32) for the CSR build. 2 atomics/edge total.
__global__ __launch_bounds__(256) void edge_stats(const float* __restrict__ ew,
                                                  const int* __restrict__ src,
                                                  const int* __restrict__ dst,
                                                  unsigned long long* __restrict__ degw,
                                                  int* __restrict__ cnt) {
  int e = blockIdx.x * blockDim.x + threadIdx.x;
  if (e >= NE) return;
  int s = src[e], d = dst[e];
  unsigned long long pk = (1ULL << 44) | (unsigned long long)(ew[e] * 4294967296.0f);
  atomicAdd(&degw[s], pk);
  atomicAdd(&cnt[d], 1);
}

// unpack degw -> deg[0:N)=wdeg_out (float), deg[N:2N)=cnt_out (float)
__global__ __launch_bounds__(256) void decode_degrees(const unsigned long long* __restrict__ degw,
                                                      float* __restrict__ deg) {
  int i = blockIdx.x * blockDim.x + threadIdx.x;
  if (i >= NN) return;
  unsigned long long v = degw[i];
  deg[i] = (float)((double)(v & ((1ULL << 44) - 1)) * (1.0 / 4294967296.0));
  deg[NN + i] = (float)(v >> 44);
}

__global__ __launch_bounds__(256) void csr_block_sums(const int* __restrict__ cnt,
                                                      int* __restrict__ part) {
  __shared__ int sh[256];
  int i = blockIdx.x * 256 + threadIdx.x;
  sh[threadIdx.x] = (i < NN) ? cnt[i] : 0;
  __syncthreads();
  for (int s = 128; s > 0; s >>= 1) {
    if (threadIdx.x < s) sh[threadIdx.x] += sh[threadIdx.x + s];
    __syncthreads();
  }
  if (threadIdx.x == 0) part[blockIdx.x] = sh[0];
}

__global__ __launch_bounds__(256) void csr_scan_part(int* __restrict__ part) {
  __shared__ int sh[256];
  int t = threadIdx.x;
  int v = (t < SCAN_BLOCKS) ? part[t] : 0;
  sh[t] = v;
  __syncthreads();
  for (int off = 1; off < 256; off <<= 1) {
    int add = (t >= off) ? sh[t - off] : 0;
    __syncthreads();
    sh[t] += add;
    __syncthreads();
  }
  if (t < SCAN_BLOCKS) part[t] = sh[t] - v;  // exclusive
}

__global__ __launch_bounds__(256) void csr_scan_write(const int* __restrict__ cnt,
                                                      const int* __restrict__ part,
                                                      int* __restrict__ row_start) {
  __shared__ int sh[256];
  int i = blockIdx.x * 256 + threadIdx.x;
  int t = threadIdx.x;
  int v = (i < NN) ? cnt[i] : 0;
  sh[t] = v;
  __syncthreads();
  for (int off = 1; off < 256; off <<= 1) {
    int add = (t >= off) ? sh[t - off] : 0;
    __syncthreads();
    sh[t] += add;
    __syncthreads();
  }
  if (i < NN) row_start[i] = part[blockIdx.x] + sh[t] - v;
  if (i == 0) row_start[NN] = NE;
}

// scatter edges into dst-sorted order; ONE 8B store per edge: (src, weight_bits)
__global__ __launch_bounds__(256) void csr_fill(const int* __restrict__ src,
                                                const int* __restrict__ dst,
                                                const float* __restrict__ ew,
                                                const int* __restrict__ row_start,
                                                int* __restrict__ fill,
                                                int2* __restrict__ psrcw) {
  int e = blockIdx.x * blockDim.x + threadIdx.x;
  if (e >= NE) return;
  int d = dst[e];
  int pos = row_start[d] + atomicAdd(&fill[d], 1);
  psrcw[pos] = make_int2(src[e], __float_as_int(ew[e]));
}

// Y[N,M] = (ELU_IN? elu(X) : X)[N,K] @ W[K,M] (+b), 4 rows/thread for W amortization.
//   RS=1: *= rsqrt(max(cnt,1)); RS=2: *= cnt>0 ? rsqrt(cnt) : 0
//   DUAL: also Y2 = X @ W2 (+b2), input staged once.
template <int K, int M, bool ELU_IN, int RS, bool DUAL>
__global__ __launch_bounds__(256) void node_gemm(const float* __restrict__ X,
                                                 const float* __restrict__ W1,
                                                 const float* __restrict__ b1,
                                                 const float* __restrict__ W2,
                                                 const float* __restrict__ b2,
                                                 const float* __restrict__ cnt,
                                                 float* __restrict__ Y1,
                                                 float* __restrict__ Y2) {
  constexpr int RPT = 4;
  constexpr int RG = 256 / M;        // row-groups per block
  constexpr int ROWS = RG * RPT;     // rows per block
  __shared__ float xs[ROWS][K];      // 2048 floats = 8KB for all instantiations
  int row0 = blockIdx.x * ROWS;
  int t = threadIdx.x;
  for (int idx = t; idx < ROWS * K; idx += 256) {
    int r = idx / K, k = idx - r * K;
    int row = row0 + r;
    float v = (row < NN) ? X[row * K + k] : 0.f;
    if (ELU_IN) v = elu1(v);
    xs[r][k] = v;
  }
  __syncthreads();
  int m = t % M, rg = t / M;
  int rbase = rg * RPT;
  float acc1[RPT], acc2[RPT];
#pragma unroll
  for (int j = 0; j < RPT; ++j) {
    acc1[j] = b1 ? b1[m] : 0.f;
    if (DUAL) acc2[j] = b2 ? b2[m] : 0.f;
  }
#pragma unroll 4
  for (int k = 0; k < K; ++k) {
    float w1 = W1[k * M + m];
    float w2 = DUAL ? W2[k * M + m] : 0.f;
#pragma unroll
    for (int j = 0; j < RPT; ++j) {
      float x = xs[rbase + j][k];
      acc1[j] += x * w1;
      if (DUAL) acc2[j] += x * w2;
    }
  }
#pragma unroll
  for (int j = 0; j < RPT; ++j) {
    int row = row0 + rbase + j;
    if (row >= NN) continue;
    float sc = 1.f;
    if (RS == 1) sc = rsqrtf(fmaxf(cnt[row], 1.f));
    if (RS == 2) {
      float wv = cnt[row];
      sc = (wv > 0.f) ? rsqrtf(wv) : 0.f;
    }
    Y1[row * M + m] = acc1[j] * sc;
    if (DUAL) Y2[row * M + m] = acc2[j] * sc;
  }
}

// Fused GATv2 layer: per dst node, single pass over in-edges; 4-way unrolled for MLP.
// HALFW: 1 -> reduce over 32-lane halves (2 heads x 32), 0 -> full 64 (1 head x 64)
template <int HALFW>
__global__ __launch_bounds__(256) void gat_fused(const int* __restrict__ row_start,
                                                 const int2* __restrict__ psrcw,
                                                 const float* __restrict__ fs,
                                                 const float* __restrict__ fd,
                                                 const float* __restrict__ attn,
                                                 float* __restrict__ g) {
  int n = blockIdx.x * 4 + (threadIdx.x >> 6);
  if (n >= NN) return;
  int lane = threadIdx.x & 63;
  int beg = row_start[n], end = row_start[n + 1];
  float fdv = fd[n * 64 + lane];
  float av = attn[lane];
  float acc = 0.f, den = 0.f;
  int i = beg;
  for (; i + 3 < end; i += 4) {
    int s0 = psrcw[i].x, s1 = psrcw[i + 1].x, s2 = psrcw[i + 2].x, s3 = psrcw[i + 3].x;
    float f0 = fs[s0 * 64 + lane];
    float f1 = fs[s1 * 64 + lane];
    float f2 = fs[s2 * 64 + lane];
    float f3 = fs[s3 * 64 + lane];
    float v0 = lrelu(f0 + fdv) * av;
    float v1 = lrelu(f1 + fdv) * av;
    float v2 = lrelu(f2 + fdv) * av;
    float v3 = lrelu(f3 + fdv) * av;
#pragma unroll
    for (int m = 16; m >= 1; m >>= 1) {
      v0 += __shfl_xor(v0, m, 64);
      v1 += __shfl_xor(v1, m, 64);
      v2 += __shfl_xor(v2, m, 64);
      v3 += __shfl_xor(v3, m, 64);
    }
    if (!HALFW) {
      v0 += __shfl_xor(v0, 32, 64);
      v1 += __shfl_xor(v1, 32, 64);
      v2 += __shfl_xor(v2, 32, 64);
      v3 += __shfl_xor(v3, 32, 64);
    }
    float p0 = __expf(v0);  // softmax shift-invariant; logits tiny -> no max pass
    float p1 = __expf(v1);
    float p2 = __expf(v2);
    float p3 = __expf(v3);
    acc += f0 * p0 + f1 * p1 + f2 * p2 + f3 * p3;
    den += p0 + p1 + p2 + p3;
  }
  for (; i < end; ++i) {
    int s = psrcw[i].x;
    float fsv = fs[s * 64 + lane];
    float v = lrelu(fsv + fdv) * av;
#pragma unroll
    for (int m = 16; m >= 1; m >>= 1) v += __shfl_xor(v, m, 64);
    if (!HALFW) v += __shfl_xor(v, 32, 64);
    float p = __expf(v);
    acc += fsv * p;
    den += p;
  }
  g[n * 64 + lane] = (end > beg) ? acc / den : 0.f;
}

// Fused GraphConv1: x3a[n] = elu( rsqrt(inw[n]) * sum_e w_e * ym[src_e] + bc1 )
// ym already carries rsqrt(outw[src]). 2 halves x 2-unroll -> 4 edges in flight.
__global__ __launch_bounds__(256) void gconv1_fused(const int* __restrict__ row_start,
                                                    const int2* __restrict__ psrcw,
                                                    const float* __restrict__ ym,
                                                    const float* __restrict__ bc1,
                                                    float* __restrict__ x3a) {
  int n = blockIdx.x * 4 + (threadIdx.x >> 6);
  if (n >= NN) return;
  int lane = threadIdx.x & 63;
  int half = lane >> 5, f = lane & 31;
  int beg = row_start[n], end = row_start[n + 1];
  float acc = 0.f, wsum = 0.f;
  int i = beg + half;
  for (; i + 2 < end; i += 4) {
    int2 a = psrcw[i], b = psrcw[i + 2];
    float wa = __int_as_float(a.y), wb = __int_as_float(b.y);
    acc += ym[a.x * 32 + f] * wa + ym[b.x * 32 + f] * wb;
    wsum += wa + wb;
  }
  if (i < end) {
    int2 a = psrcw[i];
    float wa = __int_as_float(a.y);
    acc += ym[a.x * 32 + f] * wa;
    wsum += wa;
  }
  acc += __shfl_xor(acc, 32, 64);
  wsum += __shfl_xor(wsum, 32, 64);
  if (lane < 32) {
    float r = (end > beg) ? acc * rsqrtf(wsum) : 0.f;
    x3a[n * 32 + lane] = elu1(r + bc1[lane]);
  }
}

// Fused GraphConv2: x4[n] = elu( rsqrt(max(len,1)) * sum_e xs[src] + bc2 ).
// 4 quarters x 2-unroll -> 8 edges in flight.
__global__ __launch_bounds__(256) void gconv2_fused(const int* __restrict__ row_start,
                                                    const int2* __restrict__ psrcw,
                                                    const float* __restrict__ xs,
                                                    const float* __restrict__ bc2,
                                                    float* __restrict__ x4) {
  int n = blockIdx.x * 4 + (threadIdx.x >> 6);
  if (n >= NN) return;
  int lane = threadIdx.x & 63;
  int q = lane >> 4, f = lane & 15;
  int beg = row_start[n], end = row_start[n + 1];
  float acc = 0.f;
  int i = beg + q;
  for (; i + 4 < end; i += 8) acc += xs[psrcw[i].x * 16 + f] + xs[psrcw[i + 4].x * 16 + f];
  if (i < end) acc += xs[psrcw[i].x * 16 + f];
  acc += __shfl_xor(acc, 16, 64);
  acc += __shfl_xor(acc, 32, 64);
  if (lane < 16) {
    float len = (float)(end - beg);
    x4[n * 16 + lane] = elu1(acc * rsqrtf(fmaxf(len, 1.f)) + bc2[lane]);
  }
}

// score[e, c] = concat(x4[src], x4[dst]) @ Wcls + bcls
__global__ __launch_bounds__(256) void classifier_kernel(const int* __restrict__ src,
                                                         const int* __restrict__ dst,
                                                         const float* __restrict__ x4,
                                                         const float* __restrict__ Wcls,
                                                         const float* __restrict__ bcls,
                                                         float* __restrict__ out) {
  __shared__ float w[256];
  __shared__ float bb[8];
  if (threadIdx.x < 256) w[threadIdx.x] = Wcls[threadIdx.x];
  if (threadIdx.x < 8) bb[threadIdx.x] = bcls[threadIdx.x];
  __syncthreads();
  int t = blockIdx.x * blockDim.x + threadIdx.x;
  int e = t >> 3, c = t & 7;
  if (e >= NE) return;
  int s = src[e], d = dst[e];
  float acc = bb[c];
#pragma unroll
  for (int f = 0; f < 16; ++f) acc += x4[s * 16 + f] * w[f * 8 + c];
#pragma unroll
  for (int f = 0; f < 16; ++f) acc += x4[d * 16 + f] * w[(16 + f) * 8 + c];
  out[e * 8 + c] = acc;
}

extern "C" void kernel_launch(void* const* d_in, const int* in_sizes, int n_in,
                              void* d_out, int out_size, void* d_ws, size_t ws_size,
                              hipStream_t stream) {
  const float* h      = (const float*)d_in[0];
  const float* edge_w = (const float*)d_in[1];
  const int*   src    = (const int*)d_in[2];
  const int*   dst    = (const int*)d_in[3];
  const float* Wn    = (const float*)d_in[4];
  const float* bn    = (const float*)d_in[5];
  const float* W1s   = (const float*)d_in[6];
  const float* b1s   = (const float*)d_in[7];
  const float* W1d   = (const float*)d_in[8];
  const float* b1d   = (const float*)d_in[9];
  const float* attn1 = (const float*)d_in[10];
  const float* W2s   = (const float*)d_in[11];
  const float* b2s   = (const float*)d_in[12];
  const float* W2d   = (const float*)d_in[13];
  const float* b2d   = (const float*)d_in[14];
  const float* attn2 = (const float*)d_in[15];
  const float* Wc1   = (const float*)d_in[16];
  const float* bc1   = (const float*)d_in[17];
  const float* Wc2   = (const float*)d_in[18];
  const float* bc2   = (const float*)d_in[19];
  const float* Wcls  = (const float*)d_in[20];
  const float* bcls  = (const float*)d_in[21];
  float* out = (float*)d_out;

  float* ws = (float*)d_ws;
  size_t off = 0;
  auto alloc = [&](size_t nf) { float* pp = ws + off; off += nf; return pp; };
  float* Wns = alloc(8192);
  float* Wnd = alloc(8192);
  float* bns = alloc(64);
  float* bnd = alloc(64);
  // zero region: degw(2N words) | cnt(N) | fill(N)  -> 4N words, contiguous
  unsigned long long* degw = (unsigned long long*)alloc(2 * NN);
  int*   cnt = (int*)alloc(NN);
  int*   fillp = (int*)alloc(NN);
  float* deg = alloc(2 * NN);          // decoded: wdeg_out | cnt_out (written fully by decode)
  int*   row_start = (int*)alloc(NN + 1);
  int*   part = (int*)alloc(256);      // scan partials
  int2*  psrcw = (int2*)alloc(2 * NE); // dst-sorted (src, weight_bits) pairs
  float* FS  = alloc(64 * NN);         // fs1 -> fs2 -> ym(32N) -> xs(16N)
  float* FD  = alloc(64 * NN);         // fd1 -> fd2 -> x3a(32N)
  float* G   = alloc(64 * NN);         // g1 -> g2 -> x4(16N)

  dim3 b256(256);
  const int EB = (NE + 255) / 256;
  const int NB4 = (NN + 3) / 4;

  combine_weights<<<65, b256, 0, stream>>>(Wn, bn, W1s, b1s, W1d, b1d, Wns, Wnd, bns, bnd);

  zero_kernel<<<1024, b256, 0, stream>>>((float*)degw, 4 * NN);
  edge_stats<<<EB, b256, 0, stream>>>(edge_w, src, dst, degw, cnt);
  decode_degrees<<<SCAN_BLOCKS, b256, 0, stream>>>(degw, deg);

  // CSR build (dst-sorted)
  csr_block_sums<<<SCAN_BLOCKS, b256, 0, stream>>>(cnt, part);
  csr_scan_part<<<1, b256, 0, stream>>>(part);
  csr_scan_write<<<SCAN_BLOCKS, b256, 0, stream>>>(cnt, part, row_start);
  csr_fill<<<EB, b256, 0, stream>>>(src, dst, edge_w, row_start, fillp, psrcw);

  // layer 1 fs/fd directly from h (node_f linear folded in), one dual-output GEMM
  node_gemm<128, 64, false, 0, true><<<(NN + 15) / 16, b256, 0, stream>>>(
      h, Wns, bns, Wnd, bnd, nullptr, FS, FD);
  gat_fused<1><<<NB4, b256, 0, stream>>>(row_start, psrcw, FS, FD, attn1, G);

  // layer 2 (elu fused into GEMM input read), dual; G dead after this read
  node_gemm<64, 64, true, 0, true><<<(NN + 15) / 16, b256, 0, stream>>>(
      G, W2s, b2s, W2d, b2d, nullptr, FS, FD);
  gat_fused<0><<<NB4, b256, 0, stream>>>(row_start, psrcw, FS, FD, attn2, G);

  // GraphConv 1: ym = elu(g2) @ Wc1 * rsqrt(outw)  (norm folded into GEMM);
  //              x3a = elu(rsqrt(inw)*sum(w*ym[src]) + bc1)
  node_gemm<64, 32, true, 2, false><<<(NN + 31) / 32, b256, 0, stream>>>(
      G, Wc1, nullptr, nullptr, nullptr, deg, FS, nullptr);
  gconv1_fused<<<NB4, b256, 0, stream>>>(row_start, psrcw, FS, bc1, FD);

  // GraphConv 2: xs = (x3a @ Wc2)*rsqrt(max(dout,1)) ; x4 = elu(rsqrt(din)*sum(xs[src]) + bc2)
  node_gemm<32, 16, false, 1, false><<<(NN + 63) / 64, b256, 0, stream>>>(
      FD, Wc2, nullptr, nullptr, nullptr, deg + NN, FS, nullptr);
  gconv2_fused<<<NB4, b256, 0, stream>>>(row_start, psrcw, FS, bc2, G);

  classifier_kernel<<<(NE * 8 + 255) / 256, b256, 0, stream>>>(src, dst, G, Wcls, bcls, out);
}

// Round 11
// 491.092 us; speedup vs baseline: 2.5545x; 1.0897x over previous
//
#include <hip/hip_runtime.h>
#include <math.h>

#define NN 50000
#define NE 800000

__device__ __forceinline__ float elu1(float x) { return x > 0.f ? x : expm1f(x); }
__device__ __forceinline__ float lrelu(float x) { return x >= 0.f ? x : 0.2f * x; }

// ---------------- fat0: combine_weights (blocks 0..64)  ||  zero degw+cnt (blocks 65..)
__global__ __launch_bounds__(256) void fat0_kernel(
    const float* __restrict__ Wn, const float* __restrict__ bn,
    const float* __restrict__ W1s, const float* __restrict__ b1s,
    const float* __restrict__ W1d, const float* __restrict__ b1d,
    float* __restrict__ Wns, float* __restrict__ Wnd,
    float* __restrict__ bns, float* __restrict__ bnd,
    float* __restrict__ zbase) {
  if (blockIdx.x < 65) {
    int t = blockIdx.x * 256 + threadIdx.x;
    if (t < 8192) {
      int i = t >> 6, o = t & 63;
      float acc = 0.f;
      for (int k = 0; k < 128; ++k) acc += Wn[i * 128 + k] * W1s[k * 64 + o];
      Wns[t] = acc;
    } else if (t < 16384) {
      int u = t - 8192;
      int i = u >> 6, o = u & 63;
      float acc = 0.f;
      for (int k = 0; k < 128; ++k) acc += Wn[i * 128 + k] * W1d[k * 64 + o];
      Wnd[u] = acc;
    } else if (t < 16448) {
      int o = t - 16384;
      float acc = b1s[o];
      for (int k = 0; k < 128; ++k) acc += bn[k] * W1s[k * 64 + o];
      bns[o] = acc;
    } else if (t < 16512) {
      int o = t - 16448;
      float acc = b1d[o];
      for (int k = 0; k < 128; ++k) acc += bn[k] * W1d[k * 64 + o];
      bnd[o] = acc;
    }
  } else {
    int i = (blockIdx.x - 65) * 256 + threadIdx.x;  // zero degw(2N words) + cnt(N)
    if (i < 3 * NN) zbase[i] = 0.f;
  }
}

// ---------------- pass 1: per-edge rank within its dst row (1 atomic + coalesced store)
__global__ __launch_bounds__(256) void edge_rank(const int* __restrict__ dst,
                                                 int* __restrict__ cnt,
                                                 int* __restrict__ rank) {
  int e = blockIdx.x * blockDim.x + threadIdx.x;
  if (e >= NE) return;
  rank[e] = atomicAdd(&cnt[dst[e]], 1);
}

// ---------------- single-block exclusive scan of cnt -> row_start (row_start[NN]=NE)
__global__ __launch_bounds__(1024) void scan_all(const int* __restrict__ cnt,
                                                 int* __restrict__ row_start) {
  __shared__ int sh[1024];
  int t = threadIdx.x;
  const int CHUNK = (NN + 1023) / 1024;  // 49
  int base = t * CHUNK;
  int lim = base + CHUNK;
  if (lim > NN) lim = NN;
  int s = 0;
#pragma unroll 8
  for (int i = base; i < lim; ++i) s += cnt[i];
  sh[t] = s;
  __syncthreads();
  for (int off = 1; off < 1024; off <<= 1) {
    int add = (t >= off) ? sh[t - off] : 0;
    __syncthreads();
    sh[t] += add;
    __syncthreads();
  }
  int run = sh[t] - s;  // exclusive prefix
#pragma unroll 8
  for (int i = base; i < lim; ++i) {
    row_start[i] = run;
    run += cnt[i];
  }
  if (base < NN && base + CHUNK >= NN) row_start[NN] = run;
}

// ---------------- reusable GEMM body: Y[N,M] = f(X)[N,K] @ W (+b), 4 rows/thread
template <int K, int M, bool ELU_IN, int RS, bool DUAL>
__device__ __forceinline__ void gemm_body(int blk, float* __restrict__ xs,
                                          const float* __restrict__ X,
                                          const float* __restrict__ W1,
                                          const float* __restrict__ b1,
                                          const float* __restrict__ W2,
                                          const float* __restrict__ b2,
                                          const float* __restrict__ cnt,
                                          float* __restrict__ Y1,
                                          float* __restrict__ Y2) {
  constexpr int RPT = 4;
  constexpr int ROWS = (256 / M) * RPT;
  int row0 = blk * ROWS;
  int t = threadIdx.x;
  for (int idx = t; idx < ROWS * K; idx += 256) {
    int r = idx / K, k = idx - r * K;
    int row = row0 + r;
    float v = (row < NN) ? X[row * K + k] : 0.f;
    if (ELU_IN) v = elu1(v);
    xs[r * K + k] = v;
  }
  __syncthreads();
  int m = t % M, rg = t / M;
  int rbase = rg * RPT;
  float acc1[RPT], acc2[RPT];
#pragma unroll
  for (int j = 0; j < RPT; ++j) {
    acc1[j] = b1 ? b1[m] : 0.f;
    if (DUAL) acc2[j] = b2 ? b2[m] : 0.f;
  }
#pragma unroll 4
  for (int k = 0; k < K; ++k) {
    float w1 = W1[k * M + m];
    float w2 = DUAL ? W2[k * M + m] : 0.f;
#pragma unroll
    for (int j = 0; j < RPT; ++j) {
      float x = xs[(rbase + j) * K + k];
      acc1[j] += x * w1;
      if (DUAL) acc2[j] += x * w2;
    }
  }
#pragma unroll
  for (int j = 0; j < RPT; ++j) {
    int row = row0 + rbase + j;
    if (row >= NN) continue;
    float sc = 1.f;
    if (RS == 1) sc = rsqrtf(fmaxf(cnt[row], 1.f));
    if (RS == 2) {
      float wv = cnt[row];
      sc = (wv > 0.f) ? rsqrtf(wv) : 0.f;
    }
    Y1[row * M + m] = acc1[j] * sc;
    if (DUAL) Y2[row * M + m] = acc2[j] * sc;
  }
}

template <int K, int M, bool ELU_IN, int RS, bool DUAL>
__global__ __launch_bounds__(256) void node_gemm(const float* __restrict__ X,
                                                 const float* __restrict__ W1,
                                                 const float* __restrict__ b1,
                                                 const float* __restrict__ W2,
                                                 const float* __restrict__ b2,
                                                 const float* __restrict__ cnt,
                                                 float* __restrict__ Y1,
                                                 float* __restrict__ Y2) {
  __shared__ float xs[(256 / M) * 4 * K];
  gemm_body<K, M, ELU_IN, RS, DUAL>(blockIdx.x, xs, X, W1, b1, W2, b2, cnt, Y1, Y2);
}

// ---------------- fatB: even blocks place edges (no atomic on position) + degw atomic;
//                  odd blocks run layer-1 dual GEMM (independent).
__global__ __launch_bounds__(256) void fatB_kernel(
    const int* __restrict__ src, const int* __restrict__ dst,
    const float* __restrict__ ew, const int* __restrict__ row_start,
    const int* __restrict__ rank, int2* __restrict__ psrcw,
    unsigned long long* __restrict__ degw,
    const float* __restrict__ h, const float* __restrict__ Wns,
    const float* __restrict__ bns, const float* __restrict__ Wnd,
    const float* __restrict__ bnd, float* __restrict__ FS, float* __restrict__ FD) {
  __shared__ float xs[16 * 128];
  int c = blockIdx.x >> 1;
  if (blockIdx.x & 1) {
    gemm_body<128, 64, false, 0, true>(c, xs, h, Wns, bns, Wnd, bnd, nullptr, FS, FD);
  } else {
    int e = c * 256 + threadIdx.x;
    if (e >= NE) return;
    int s = src[e], d = dst[e];
    float w = ew[e];
    psrcw[row_start[d] + rank[e]] = make_int2(s, __float_as_int(w));
    unsigned long long pk = (1ULL << 44) | (unsigned long long)(w * 4294967296.0f);
    atomicAdd(&degw[s], pk);
  }
}

// ---------------- fatL2: layer-2 dual GEMM || decode degrees
__global__ __launch_bounds__(256) void fatL2_kernel(
    const float* __restrict__ G, const float* __restrict__ W2s,
    const float* __restrict__ b2s, const float* __restrict__ W2d,
    const float* __restrict__ b2d, float* __restrict__ FS, float* __restrict__ FD,
    const unsigned long long* __restrict__ degw, float* __restrict__ deg) {
  __shared__ float xs[16 * 64];
  if (blockIdx.x < 3125) {
    gemm_body<64, 64, true, 0, true>(blockIdx.x, xs, G, W2s, b2s, W2d, b2d, nullptr, FS, FD);
  } else {
    int i = (blockIdx.x - 3125) * 256 + threadIdx.x;
    if (i >= NN) return;
    unsigned long long v = degw[i];
    deg[i] = (float)((double)(v & ((1ULL << 44) - 1)) * (1.0 / 4294967296.0));
    deg[NN + i] = (float)(v >> 44);
  }
}

// ---------------- Fused GATv2 layer (wave per dst node, 4-way unrolled)
template <int HALFW>
__global__ __launch_bounds__(256) void gat_fused(const int* __restrict__ row_start,
                                                 const int2* __restrict__ psrcw,
                                                 const float* __restrict__ fs,
                                                 const float* __restrict__ fd,
                                                 const float* __restrict__ attn,
                                                 float* __restrict__ g) {
  int n = blockIdx.x * 4 + (threadIdx.x >> 6);
  if (n >= NN) return;
  int lane = threadIdx.x & 63;
  int beg = row_start[n], end = row_start[n + 1];
  float fdv = fd[n * 64 + lane];
  float av = attn[lane];
  float acc = 0.f, den = 0.f;
  int i = beg;
  for (; i + 3 < end; i += 4) {
    int s0 = psrcw[i].x, s1 = psrcw[i + 1].x, s2 = psrcw[i + 2].x, s3 = psrcw[i + 3].x;
    float f0 = fs[s0 * 64 + lane];
    float f1 = fs[s1 * 64 + lane];
    float f2 = fs[s2 * 64 + lane];
    float f3 = fs[s3 * 64 + lane];
    float v0 = lrelu(f0 + fdv) * av;
    float v1 = lrelu(f1 + fdv) * av;
    float v2 = lrelu(f2 + fdv) * av;
    float v3 = lrelu(f3 + fdv) * av;
#pragma unroll
    for (int m = 16; m >= 1; m >>= 1) {
      v0 += __shfl_xor(v0, m, 64);
      v1 += __shfl_xor(v1, m, 64);
      v2 += __shfl_xor(v2, m, 64);
      v3 += __shfl_xor(v3, m, 64);
    }
    if (!HALFW) {
      v0 += __shfl_xor(v0, 32, 64);
      v1 += __shfl_xor(v1, 32, 64);
      v2 += __shfl_xor(v2, 32, 64);
      v3 += __shfl_xor(v3, 32, 64);
    }
    float p0 = __expf(v0);  // softmax shift-invariant; logits tiny -> no max pass
    float p1 = __expf(v1);
    float p2 = __expf(v2);
    float p3 = __expf(v3);
    acc += f0 * p0 + f1 * p1 + f2 * p2 + f3 * p3;
    den += p0 + p1 + p2 + p3;
  }
  for (; i < end; ++i) {
    int s = psrcw[i].x;
    float fsv = fs[s * 64 + lane];
    float v = lrelu(fsv + fdv) * av;
#pragma unroll
    for (int m = 16; m >= 1; m >>= 1) v += __shfl_xor(v, m, 64);
    if (!HALFW) v += __shfl_xor(v, 32, 64);
    float p = __expf(v);
    acc += fsv * p;
    den += p;
  }
  g[n * 64 + lane] = (end > beg) ? acc / den : 0.f;
}

// ---------------- Fused GraphConv1 (ym carries rsqrt(outw); inw from row weight sum)
__global__ __launch_bounds__(256) void gconv1_fused(const int* __restrict__ row_start,
                                                    const int2* __restrict__ psrcw,
                                                    const float* __restrict__ ym,
                                                    const float* __restrict__ bc1,
                                                    float* __restrict__ x3a) {
  int n = blockIdx.x * 4 + (threadIdx.x >> 6);
  if (n >= NN) return;
  int lane = threadIdx.x & 63;
  int half = lane >> 5, f = lane & 31;
  int beg = row_start[n], end = row_start[n + 1];
  float acc = 0.f, wsum = 0.f;
  int i = beg + half;
  for (; i + 2 < end; i += 4) {
    int2 a = psrcw[i], b = psrcw[i + 2];
    float wa = __int_as_float(a.y), wb = __int_as_float(b.y);
    acc += ym[a.x * 32 + f] * wa + ym[b.x * 32 + f] * wb;
    wsum += wa + wb;
  }
  if (i < end) {
    int2 a = psrcw[i];
    float wa = __int_as_float(a.y);
    acc += ym[a.x * 32 + f] * wa;
    wsum += wa;
  }
  acc += __shfl_xor(acc, 32, 64);
  wsum += __shfl_xor(wsum, 32, 64);
  if (lane < 32) {
    float r = (end > beg) ? acc * rsqrtf(wsum) : 0.f;
    x3a[n * 32 + lane] = elu1(r + bc1[lane]);
  }
}

// ---------------- Fused GraphConv2
__global__ __launch_bounds__(256) void gconv2_fused(const int* __restrict__ row_start,
                                                    const int2* __restrict__ psrcw,
                                                    const float* __restrict__ xs,
                                                    const float* __restrict__ bc2,
                                                    float* __restrict__ x4) {
  int n = blockIdx.x * 4 + (threadIdx.x >> 6);
  if (n >= NN) return;
  int lane = threadIdx.x & 63;
  int q = lane >> 4, f = lane & 15;
  int beg = row_start[n], end = row_start[n + 1];
  float acc = 0.f;
  int i = beg + q;
  for (; i + 4 < end; i += 8) acc += xs[psrcw[i].x * 16 + f] + xs[psrcw[i + 4].x * 16 + f];
  if (i < end) acc += xs[psrcw[i].x * 16 + f];
  acc += __shfl_xor(acc, 16, 64);
  acc += __shfl_xor(acc, 32, 64);
  if (lane < 16) {
    float len = (float)(end - beg);
    x4[n * 16 + lane] = elu1(acc * rsqrtf(fmaxf(len, 1.f)) + bc2[lane]);
  }
}

// ---------------- classifier: 2 threads/edge, float4 loads + float4 store
__global__ __launch_bounds__(256) void classifier_kernel(const int* __restrict__ src,
                                                         const int* __restrict__ dst,
                                                         const float* __restrict__ x4,
                                                         const float* __restrict__ Wcls,
                                                         const float* __restrict__ bcls,
                                                         float* __restrict__ out) {
  __shared__ float w[256];
  __shared__ float bb[8];
  if (threadIdx.x < 256) w[threadIdx.x] = Wcls[threadIdx.x];
  if (threadIdx.x < 8) bb[threadIdx.x] = bcls[threadIdx.x];
  __syncthreads();
  int t = blockIdx.x * blockDim.x + threadIdx.x;
  int e = t >> 1, c0 = (t & 1) * 4;
  if (e >= NE) return;
  int s = src[e], d = dst[e];
  const float4* xsv = (const float4*)&x4[s * 16];
  const float4* xdv = (const float4*)&x4[d * 16];
  float acc0 = bb[c0], acc1 = bb[c0 + 1], acc2 = bb[c0 + 2], acc3 = bb[c0 + 3];
#pragma unroll
  for (int q = 0; q < 4; ++q) {
    float4 xv = xsv[q];
#pragma unroll
    for (int j = 0; j < 4; ++j) {
      float x = j == 0 ? xv.x : j == 1 ? xv.y : j == 2 ? xv.z : xv.w;
      const float* wr = &w[(q * 4 + j) * 8 + c0];
      acc0 += x * wr[0];
      acc1 += x * wr[1];
      acc2 += x * wr[2];
      acc3 += x * wr[3];
    }
  }
#pragma unroll
  for (int q = 0; q < 4; ++q) {
    float4 xv = xdv[q];
#pragma unroll
    for (int j = 0; j < 4; ++j) {
      float x = j == 0 ? xv.x : j == 1 ? xv.y : j == 2 ? xv.z : xv.w;
      const float* wr = &w[(16 + q * 4 + j) * 8 + c0];
      acc0 += x * wr[0];
      acc1 += x * wr[1];
      acc2 += x * wr[2];
      acc3 += x * wr[3];
    }
  }
  *(float4*)&out[e * 8 + c0] = make_float4(acc0, acc1, acc2, acc3);
}

extern "C" void kernel_launch(void* const* d_in, const int* in_sizes, int n_in,
                              void* d_out, int out_size, void* d_ws, size_t ws_size,
                              hipStream_t stream) {
  const float* h      = (const float*)d_in[0];
  const float* edge_w = (const float*)d_in[1];
  const int*   src    = (const int*)d_in[2];
  const int*   dst    = (const int*)d_in[3];
  const float* Wn    = (const float*)d_in[4];
  const float* bn    = (const float*)d_in[5];
  const float* W1s   = (const float*)d_in[6];
  const float* b1s   = (const float*)d_in[7];
  const float* W1d   = (const float*)d_in[8];
  const float* b1d   = (const float*)d_in[9];
  const float* attn1 = (const float*)d_in[10];
  const float* W2s   = (const float*)d_in[11];
  const float* b2s   = (const float*)d_in[12];
  const float* W2d   = (const float*)d_in[13];
  const float* b2d   = (const float*)d_in[14];
  const float* attn2 = (const float*)d_in[15];
  const float* Wc1   = (const float*)d_in[16];
  const float* bc1   = (const float*)d_in[17];
  const float* Wc2   = (const float*)d_in[18];
  const float* bc2   = (const float*)d_in[19];
  const float* Wcls  = (const float*)d_in[20];
  const float* bcls  = (const float*)d_in[21];
  float* out = (float*)d_out;

  float* ws = (float*)d_ws;
  size_t off = 0;
  // round every allocation to 4 floats so int2/float4 views stay 16B-aligned
  auto alloc = [&](size_t nf) { float* pp = ws + off; off += (nf + 3) & ~(size_t)3; return pp; };
  float* Wns = alloc(8192);
  float* Wnd = alloc(8192);
  float* bns = alloc(64);
  float* bnd = alloc(64);
  // zero region: degw (2N words) | cnt (N)  -> 3N words contiguous
  unsigned long long* degw = (unsigned long long*)alloc(2 * NN);
  int*   cnt = (int*)alloc(NN);
  float* deg = alloc(2 * NN);          // decoded wdeg_out | cnt_out (fully written)
  int*   row_start = (int*)alloc(NN + 1);
  int2*  psrcw = (int2*)alloc(2 * NE); // dst-sorted (src, weight_bits)
  float* FS  = alloc(64 * NN);         // fs1 -> fs2 -> ym(32N) -> xs(16N)
  float* FD  = alloc(64 * NN);         // fd1 -> fd2 -> x3a(32N)
  float* G   = alloc(64 * NN);         // g1 -> g2 -> x4(16N); first NE words double as rank[]
  int*   rank = (int*)G;               // rank dead before gat1 writes G

  dim3 b256(256);
  const int EB = (NE + 255) / 256;     // 3125
  const int NB4 = (NN + 3) / 4;        // 12500

  // 1. combine weights || zero degw+cnt
  fat0_kernel<<<65 + (3 * NN + 255) / 256, b256, 0, stream>>>(
      Wn, bn, W1s, b1s, W1d, b1d, Wns, Wnd, bns, bnd, (float*)degw);
  // 2. per-edge dst rank (1 atomic/edge)
  edge_rank<<<EB, b256, 0, stream>>>(dst, cnt, rank);
  // 3. row_start = exclusive scan of cnt (single block)
  scan_all<<<1, 1024, 0, stream>>>(cnt, row_start);
  // 4. place edges (no position atomic) + degw atomics  ||  layer-1 dual GEMM
  fatB_kernel<<<2 * EB, b256, 0, stream>>>(src, dst, edge_w, row_start, rank, psrcw,
                                           degw, h, Wns, bns, Wnd, bnd, FS, FD);
  // 5. GAT layer 1
  gat_fused<1><<<NB4, b256, 0, stream>>>(row_start, psrcw, FS, FD, attn1, G);
  // 6. layer-2 dual GEMM || decode degrees
  fatL2_kernel<<<3125 + (NN + 255) / 256, b256, 0, stream>>>(G, W2s, b2s, W2d, b2d,
                                                             FS, FD, degw, deg);
  // 7. GAT layer 2
  gat_fused<0><<<NB4, b256, 0, stream>>>(row_start, psrcw, FS, FD, attn2, G);
  // 8. ym = elu(g2) @ Wc1 * rsqrt(outw)
  node_gemm<64, 32, true, 2, false><<<(NN + 31) / 32, b256, 0, stream>>>(
      G, Wc1, nullptr, nullptr, nullptr, deg, FS, nullptr);
  // 9. GraphConv1 aggregate
  gconv1_fused<<<NB4, b256, 0, stream>>>(row_start, psrcw, FS, bc1, FD);
  // 10. xs = (x3a @ Wc2) * rsqrt(max(dout,1))
  node_gemm<32, 16, false, 1, false><<<(NN + 63) / 64, b256, 0, stream>>>(
      FD, Wc2, nullptr, nullptr, nullptr, deg + NN, FS, nullptr);
  // 11. GraphConv2 aggregate
  gconv2_fused<<<NB4, b256, 0, stream>>>(row_start, psrcw, FS, bc2, G);
  // 12. per-edge classifier
  classifier_kernel<<<(NE * 2 + 255) / 256, b256, 0, stream>>>(src, dst, G, Wcls, bcls, out);
}